// Round 10
// baseline (554.480 us; speedup 1.0000x reference)
//
#include <hip/hip_runtime.h>
#include <hip/hip_bf16.h>
#include <stdint.h>

// Problem constants (B,H,S,D) = (2,16,2048,64); softmax is over the HEAD axis.
#define B_ 2
#define H_ 16
#define S_ 2048
#define D_ 64

typedef __attribute__((ext_vector_type(8))) short bf16x8;
typedef __attribute__((ext_vector_type(4))) float f32x4;
typedef __attribute__((ext_vector_type(4))) unsigned short u16x4;

__device__ __forceinline__ short f2bf(float x){
  union { float f; uint32_t u; } v; v.f = x;
  uint32_t r = v.u + 0x7FFFu + ((v.u >> 16) & 1u);   // round-to-nearest-even
  return (short)(r >> 16);
}
__device__ __forceinline__ float bf2f(short s){
  union { uint32_t u; float f; } v; v.u = ((uint32_t)(uint16_t)s) << 16;
  return v.f;
}

// LDS swizzle: w(q) = ((q>>2)<<1)|(q&1) — bijective 3-bit map; spreads the
// 16B-granular accesses of rows across 8 distinct bank windows.
__device__ __forceinline__ int wfun(int x){ return (((x >> 2) << 1) | (x & 1)) & 7; }

// ---------- prep 1: fp32 -> bf16 ----------
__global__ __launch_bounds__(256) void cast_bf16(const float* __restrict__ X,
                                                 short* __restrict__ Y){
  size_t idx = ((size_t)blockIdx.x * 256 + threadIdx.x) * 8;
  float4 a = *(const float4*)(X + idx);
  float4 b = *(const float4*)(X + idx + 4);
  bf16x8 v;
  v[0]=f2bf(a.x); v[1]=f2bf(a.y); v[2]=f2bf(a.z); v[3]=f2bf(a.w);
  v[4]=f2bf(b.x); v[5]=f2bf(b.y); v[6]=f2bf(b.z); v[7]=f2bf(b.w);
  *(bf16x8*)(Y + idx) = v;
}

// ---------- prep 2: V -> Vt[b,h,d,k] bf16 (transposed) ----------
__global__ __launch_bounds__(256) void transpose_v(const float* __restrict__ V,
                                                   short* __restrict__ Vt){
  __shared__ float T[64][65];
  int bh = blockIdx.x >> 5;          // 0..31  (B*H)
  int k0 = (blockIdx.x & 31) * 64;   // S/64 = 32 chunks
  int t = threadIdx.x;
  {
    int col = (t & 15) * 4;          // d
    #pragma unroll
    for (int i = 0; i < 4; ++i){
      int row = (t >> 4) + i * 16;   // k within chunk
      float4 a = *(const float4*)(V + ((size_t)bh * S_ + k0 + row) * D_ + col);
      T[col+0][row] = a.x; T[col+1][row] = a.y; T[col+2][row] = a.z; T[col+3][row] = a.w;
    }
  }
  __syncthreads();
  {
    int d  = t >> 2;
    int kk = (t & 3) * 16;
    bf16x8 o0, o1;
    #pragma unroll
    for (int j = 0; j < 8; ++j){
      o0[j] = f2bf(T[d][kk + j]);
      o1[j] = f2bf(T[d][kk + 8 + j]);
    }
    short* dst = Vt + ((size_t)bh * D_ + d) * S_ + k0 + kk;
    *(bf16x8*)(dst)     = o0;
    *(bf16x8*)(dst + 8) = o1;
  }
}

// ---------- pass 1: Z[b,q,k] = masked ? -1 : 1/sum_h exp(s_h/8) ----------
__global__ __launch_bounds__(256, 4) void pass1(const short* __restrict__ Qb,
                                                const short* __restrict__ Kb,
                                                const int* __restrict__ mask,
                                                float* __restrict__ Z){
  const int tid = threadIdx.x, w = tid >> 6, lane = tid & 63;
  const int g = lane >> 4, lr = lane & 15;
  const int bid = blockIdx.x;
  const int qg    = bid & 31;          // 32 q-groups of 64
  const int strip = (bid >> 5) & 15;   // 16 k-strips of 128
  const int b     = bid >> 9;
  const int q0 = qg * 64 + w * 16;
  const int ks = strip * 128;

  float dsum[8][4];
  #pragma unroll
  for (int st = 0; st < 8; ++st)
    #pragma unroll
    for (int r = 0; r < 4; ++r) dsum[st][r] = 0.f;

  for (int h = 0; h < 16; ++h){
    const size_t bh = (size_t)b * H_ + h;
    const short* qp = Qb + (bh * S_ + q0 + lr) * D_ + g * 8;
    bf16x8 qf0 = *(const bf16x8*)(qp);
    bf16x8 qf1 = *(const bf16x8*)(qp + 32);
    const short* kp = Kb + (bh * S_ + ks + lr) * D_ + g * 8;
    #pragma unroll 4
    for (int st = 0; st < 8; ++st){
      bf16x8 kf0 = *(const bf16x8*)(kp + (size_t)(st*16) * D_);
      bf16x8 kf1 = *(const bf16x8*)(kp + (size_t)(st*16) * D_ + 32);
      f32x4 s = (f32x4){0.f,0.f,0.f,0.f};
      s = __builtin_amdgcn_mfma_f32_16x16x32_bf16(qf0, kf0, s, 0, 0, 0);
      s = __builtin_amdgcn_mfma_f32_16x16x32_bf16(qf1, kf1, s, 0, 0, 0);
      #pragma unroll
      for (int r = 0; r < 4; ++r) dsum[st][r] += __expf(s[r] * 0.125f);
    }
  }

  #pragma unroll
  for (int st = 0; st < 8; ++st){
    #pragma unroll
    for (int r = 0; r < 4; ++r){
      const size_t qrow = (size_t)b * S_ + q0 + 4*g + r;
      const int kk = ks + st*16 + lr;
      int m = mask[qrow * S_ + kk];
      Z[qrow * S_ + kk] = m ? (1.0f / dsum[st][r]) : -1.0f;
    }
  }
}

// ---------- pass 2: p = z<0 ? 1/16 : exp(s/8)*z ; store p ; out = P V ----------
// 512 blocks x 512 thr (8 waves); wave = (b,h,q16). NO barriers. p is staged
// in a wave-private LDS tile [16 q][256 k] (bf16, swizzled) and flushed
// row-major every 4 k-iters: 1 instruction = 1 KB contiguous (fillBuffer-like
// bursts). Next sub-tile's loads are issued BEFORE the flush stores so load
// waits never drain stores (in-order vmcnt).
__global__ __launch_bounds__(512, 4) void pass2(const short* __restrict__ Qb,
                                                const short* __restrict__ Kb,
                                                const short* __restrict__ Vt,
                                                const float* __restrict__ Z,
                                                float* __restrict__ out,
                                                float* __restrict__ pout){
  __shared__ short pl[8][16][256];   // 64 KB: [wave][q][k-swizzled]

  const int tid = threadIdx.x, w = tid >> 6, lane = tid & 63;
  const int g = lane >> 4, lr = lane & 15;
  const int bid = blockIdx.x;
  const int strip = bid >> 5, b = (bid >> 4) & 1, h = bid & 15;
  const int q0 = strip * 128 + w * 16;
  const size_t bh = (size_t)b * 16 + h;

  bf16x8 qf0, qf1;
  {
    const short* qp = Qb + (bh * S_ + q0 + lr) * D_ + g * 8;
    qf0 = *(const bf16x8*)(qp);
    qf1 = *(const bf16x8*)(qp + 32);
  }

  f32x4 o[4];
  #pragma unroll
  for (int j = 0; j < 4; ++j) o[j] = (f32x4){0.f,0.f,0.f,0.f};

  const short* kb = Kb + (bh * S_ + lr) * D_ + g * 8;
  const short* vb = Vt + (bh * D_ + lr) * S_ + g * 8;
  const float* zl = Z    + ((size_t)b * S_ + q0 + 4*g) * S_ + lr;
  float*       prow = pout + (bh * S_ + q0) * S_;   // flush base (row-major)
  short*       plw = &pl[w][0][0];
  const int wl8 = 8 * wfun(lr);            // read-side swizzle (row q = lr)

  f32x4 zv[4];
  bf16x8 kh[4][2];
  bf16x8 vr[4][2];

  // issue loads for (sup, sub) into zv/kh/vr
  auto load_all = [&](int k0){
    #pragma unroll
    for (int t = 0; t < 4; ++t)
      #pragma unroll
      for (int r = 0; r < 4; ++r)
        zv[t][r] = zl[(size_t)r * S_ + k0 + 16*t];
    #pragma unroll
    for (int t = 0; t < 4; ++t){
      kh[t][0] = *(const bf16x8*)(kb + (size_t)(k0 + 16*t) * D_);
      kh[t][1] = *(const bf16x8*)(kb + (size_t)(k0 + 16*t) * D_ + 32);
    }
    #pragma unroll
    for (int j = 0; j < 4; ++j)
      #pragma unroll
      for (int m = 0; m < 2; ++m)
        vr[j][m] = *(const bf16x8*)(vb + (size_t)(16*j) * S_ + k0 + 32*m);
  };

  // compute one 16q x 64k sub-tile: QK^T, p -> LDS, transpose-read, PV
  auto compute = [&](int sub, int k0){
    f32x4 s[4];
    #pragma unroll
    for (int t = 0; t < 4; ++t){
      s[t] = (f32x4){0.f,0.f,0.f,0.f};
      s[t] = __builtin_amdgcn_mfma_f32_16x16x32_bf16(qf0, kh[t][0], s[t], 0, 0, 0);
      s[t] = __builtin_amdgcn_mfma_f32_16x16x32_bf16(qf1, kh[t][1], s[t], 0, 0, 0);
    }
    #pragma unroll
    for (int t = 0; t < 4; ++t){
      #pragma unroll
      for (int r = 0; r < 4; ++r){
        float e = __expf(s[t][r] * 0.125f);
        float z = zv[t][r];
        float p = (z < 0.f) ? 0.0625f : e * z;
        int q = 4*g + r;
        int el = (sub*64 + 16*t + lr) ^ (8 * wfun(q));   // XOR hits bits [5:3] only
        plw[q*256 + el] = f2bf(p);
      }
    }
    bf16x8 pa0 = *(const bf16x8*)(plw + lr*256 + sub*64 + ((8*g)      ^ wl8));
    bf16x8 pa1 = *(const bf16x8*)(plw + lr*256 + sub*64 + ((32 + 8*g) ^ wl8));
    #pragma unroll
    for (int j = 0; j < 4; ++j){
      o[j] = __builtin_amdgcn_mfma_f32_16x16x32_bf16(pa0, vr[j][0], o[j], 0, 0, 0);
      o[j] = __builtin_amdgcn_mfma_f32_16x16x32_bf16(pa1, vr[j][1], o[j], 0, 0, 0);
    }
  };

  // flush super-tile ps: 16 instructions, each 1 full row = 1 KB contiguous
  auto flush = [&](int ps){
    #pragma unroll
    for (int row = 0; row < 16; ++row){
      int el = (4*lane) ^ (8 * wfun(row));
      u16x4 pb = *(const u16x4*)(plw + row*256 + el);
      f32x4 pf;
      #pragma unroll
      for (int i = 0; i < 4; ++i) pf[i] = bf2f((short)pb[i]);
      *(f32x4*)(prow + (size_t)row * S_ + ps*256 + 4*lane) = pf;
    }
  };

  for (int sup = 0; sup < 8; ++sup){
    const int kb0 = sup * 256;
    load_all(kb0);                 // sub-0 loads issued BEFORE flush stores
    if (sup > 0) flush(sup - 1);   // stores of previous super-tile
    compute(0, kb0);
    #pragma unroll
    for (int sub = 1; sub < 4; ++sub){
      load_all(kb0 + sub*64);
      compute(sub, kb0 + sub*64);
    }
  }
  flush(7);

  // epilogue
  #pragma unroll
  for (int j = 0; j < 4; ++j)
    #pragma unroll
    for (int r = 0; r < 4; ++r)
      out[(bh * S_ + q0 + 4*g + r) * D_ + 16*j + lr] = o[j][r];
}

extern "C" void kernel_launch(void* const* d_in, const int* in_sizes, int n_in,
                              void* d_out, int out_size, void* d_ws, size_t ws_size,
                              hipStream_t stream){
  const float* Q    = (const float*)d_in[0];
  const float* K    = (const float*)d_in[1];
  const float* V    = (const float*)d_in[2];
  const int*   mask = (const int*)d_in[3];

  const size_t nkv = (size_t)B_ * H_ * S_ * D_;   // 4,194,304

  short* Qb  = (short*)d_ws;                       // 8.4 MB
  short* Kb  = Qb + nkv;                           // 8.4 MB
  short* Vt  = Kb + nkv;                           // 8.4 MB
  float* Zb  = (float*)(Vt + nkv);                 // 33.5 MB (B*S*S fp32)

  float* out  = (float*)d_out;        // [B,H,S,D]
  float* pout = out + nkv;            // [B,H,S,S]

  cast_bf16  <<<(int)(nkv / (256 * 8)), 256, 0, stream>>>(Q, Qb);
  cast_bf16  <<<(int)(nkv / (256 * 8)), 256, 0, stream>>>(K, Kb);
  transpose_v<<<B_ * H_ * (S_ / 64),    256, 0, stream>>>(V, Vt);
  pass1      <<<1024,                   256, 0, stream>>>(Qb, Kb, mask, Zb);
  pass2      <<<512,                    512, 0, stream>>>(Qb, Kb, Vt, Zb, out, pout);
}